// Round 22
// baseline (92.525 us; speedup 1.0000x reference)
//
#include <hip/hip_runtime.h>
#include <math.h>

#define NSHOT 5
#define WAY 32
#define DIM 640
#define NQ 4096
#define RNEAR 10

// ---- workspace layout (float offsets), ~1.08 MB ----
constexpr int OFF_PROTOS = 0;        // 32*640
constexpr int OFF_QPART  = 20480;    // 128*640 column partial sums (incl. shot fold)
constexpr int OFF_C      = 102400;   // 32
constexpr int OFF_BETA   = 102432;   // 32
constexpr int OFF_S      = 102464;   // 32
constexpr int OFF_U      = 102496;   // 32
constexpr int OFF_NID    = 102528;   // 32*10
constexpr int OFF_RR     = 102848;   // 32*22
constexpr int OFF_SPC    = 103552;   // 32
constexpr int OFF_H1P    = 103584;   // 32*128 (per-way pr·W1a)
constexpr int OFF_TP     = 107680;   // 32*640
constexpr int OFF_G      = 128160;   // 32*4096 f32 DISTANCES (written by gemm mode 0)
constexpr int OFF_NIDX   = 259232;   // 32*10 ints
constexpr int OFF_Q2D    = 259556;   // double[4096] (byte-offset %8 == 0)
constexpr int OFF_X2D    = 267748;   // double[32] (proto_p norm^2)
constexpr int OFF_X2D2   = 267812;   // double[32] (test_proto norm^2)
constexpr int OFF_P2RAW  = 267876;   // double[32] (raw proto norm^2)
constexpr int OFF_H1PART = 268000;   // 8*128 way-independent h1 partials
constexpr int OFF_CNT    = 269024;   // 1 int (amw1 tail counter)

__device__ __forceinline__ double wave_sum_d(double v) {
#pragma unroll
  for (int o = 32; o > 0; o >>= 1) v += __shfl_down(v, o, 64);
  return v;
}

__device__ __forceinline__ float aloadf(const float* p) {
  return __hip_atomic_load(p, __ATOMIC_RELAXED, __HIP_MEMORY_SCOPE_AGENT);
}
__device__ __forceinline__ int aloadi(const int* p) {
  return __hip_atomic_load(p, __ATOMIC_RELAXED, __HIP_MEMORY_SCOPE_AGENT);
}

// f32 fast distance — used for BOTH the selection path and the output path
// (reference itself computes dis_mat in f32; bf16-scale threshold 1.98e-2)
__device__ __forceinline__ float dist_f32(float c, float xdotq, float u2, float q2) {
  const float EPSf = 1e-5f;
  float sc = sqrtf(c);
  float nq = sqrtf(q2);
  float nf = fmaxf(nq, EPSf);
  float th = tanhf(sc * nf);
  float al = th / (sc * nf);
  float ny = fmaxf(al * nq, EPSf);
  float mx = 0.999f / sc;
  if (ny > mx) al *= mx / ny;
  float y2 = al * al * q2;
  float uy = -al * xdotq;
  float A = 1.f + 2.f * c * uy + c * y2;
  float B = 1.f - c * u2;
  float den = fmaxf(1.f + 2.f * c * uy + c * c * u2 * y2, EPSf);
  float num2 = fmaxf(A * A * u2 + 2.f * A * B * uy + B * B * y2, 0.f);
  float n = sqrtf(num2) / den;
  float arg = sc * n;
  arg = fminf(fmaxf(arg, 0.f), 1.f - 1e-5f);
  return (1.f / sc) * logf((1.f + arg) / (1.f - arg));
}

__device__ __forceinline__ double expmap_scale(double c, double p2, double* u2out) {
  double sc = sqrt(c);
  double ntrue = sqrt(p2);
  double nf = fmax(ntrue, 1e-5);
  double th = tanh(sc * nf);
  double s0 = th / (sc * nf);
  double ny = fmax(s0 * ntrue, 1e-5);
  double mx = 0.999 / sc;
  if (ny > mx) s0 *= mx / ny;
  *u2out = s0 * s0 * p2;
  return s0;
}

// grid 128 x 640: protos + P2RAW + H1P (b<32), per-row q2, QPART (+shot fold), CNT reset
__global__ __launch_bounds__(640) void k_fuse1(const float* __restrict__ Qm,
                                               const float* __restrict__ shot,
                                               const float* __restrict__ W1, float* ws) {
  __shared__ double q2w[32][10];
  __shared__ double psred[10];
  __shared__ float pr[DIM];
  __shared__ float h1pp[5][128];
  int b = blockIdx.x, t = threadIdx.x;
  int lane = t & 63, wid = t >> 6;  // 10 waves
  float protoval = 0.f;
  if (b < WAY) {
    float s = 0.f;
#pragma unroll
    for (int s5 = 0; s5 < NSHOT; ++s5) s += shot[(size_t)(s5 * WAY + b) * DIM + t];
    protoval = s * 0.2f;
    pr[t] = protoval;
    ws[OFF_PROTOS + b * DIM + t] = protoval;
    double pv2 = (double)protoval * protoval;
    pv2 = wave_sum_d(pv2);
    if (lane == 0) psred[wid] = pv2;
  }
  int r0 = b * 32;
  float colacc = 0.f;
  for (int r = 0; r < 32; ++r) {
    float v = Qm[(size_t)(r0 + r) * DIM + t];
    colacc += v;
    double sq = (double)v * v;
    sq = wave_sum_d(sq);
    if (lane == 0) q2w[r][wid] = sq;
  }
  ws[OFF_QPART + b * DIM + t] = colacc + 5.f * protoval;
  __syncthreads();
  if (t < 32) {
    double s = 0.0;
#pragma unroll
    for (int k = 0; k < 10; ++k) s += q2w[t][k];
    ((double*)(ws + OFF_Q2D))[r0 + t] = s;
  }
  if (b < WAY) {
    int n = t & 127, s = t >> 7;
    int k0 = s * 128;
    float acc = 0.f;
#pragma unroll 8
    for (int k = k0; k < k0 + 128; ++k) acc = fmaf(pr[k], W1[(size_t)k * 128 + n], acc);
    h1pp[s][n] = acc;
    __syncthreads();
    if (t < 128)
      ws[OFF_H1P + b * 128 + t] = h1pp[0][t] + h1pp[1][t] + h1pp[2][t] + h1pp[3][t] + h1pp[4][t];
    if (t == 0) {
      double p2 = 0.0;
#pragma unroll
      for (int k = 0; k < 10; ++k) p2 += psred[k];
      ((double*)(ws + OFF_P2RAW))[b] = p2;
    }
  }
  if (b == 0 && t == 0) ((int*)(ws + OFF_CNT))[0] = 0;
}

// grid 8 x 640: way-independent am+W1b (once); last-done block runs the tiny
// per-way MLP tail (h1 sum -> h2 -> logits -> softmax -> C/BETA/X2D) for all ways.
__global__ __launch_bounds__(640) void k_amw1(const float* __restrict__ W1, const float* __restrict__ b1,
                                              const float* __restrict__ W2, const float* __restrict__ b2,
                                              const float* __restrict__ W3, const float* __restrict__ b3,
                                              float* ws) {
  __shared__ float part_am[4][80];
  __shared__ float am_s[80];
  __shared__ float h1part_l[2][128];
  __shared__ int tailflag;
  __shared__ float hp[8][128];
  __shared__ float h1all[32][128];
  __shared__ float h2all[32][64];
  int j = blockIdx.x, t = threadIdx.x;
  if (t < 320) {
    int c = t % 80, pg = t / 80;   // 4 p-groups x 32
    const float* base = ws + OFF_QPART + j * 80 + c;
    int p0 = pg * 32;
    float a0 = 0.f, a1 = 0.f, a2 = 0.f, a3 = 0.f;
#pragma unroll 8
    for (int p = 0; p < 32; p += 4) {
      a0 += base[(size_t)(p0 + p + 0) * DIM];
      a1 += base[(size_t)(p0 + p + 1) * DIM];
      a2 += base[(size_t)(p0 + p + 2) * DIM];
      a3 += base[(size_t)(p0 + p + 3) * DIM];
    }
    part_am[pg][c] = (a0 + a1) + (a2 + a3);
  }
  __syncthreads();
  if (t < 80)
    am_s[t] = (part_am[0][t] + part_am[1][t] + part_am[2][t] + part_am[3][t]) * (1.f / 4256.f);
  __syncthreads();
  if (t < 256) {
    int n = t & 127, kh = t >> 7;      // 2 k-halves x 40
    int kbase = j * 80 + kh * 40;
    float acc = 0.f;
#pragma unroll 8
    for (int k = 0; k < 40; ++k)
      acc = fmaf(am_s[kh * 40 + k], W1[(size_t)(DIM + kbase + k) * 128 + n], acc);
    h1part_l[kh][n] = acc;
  }
  __syncthreads();
  if (t < 128) ws[OFF_H1PART + j * 128 + t] = h1part_l[0][t] + h1part_l[1][t];
  // ---- last-done block runs the tiny ctrl tail ----
  __threadfence();
  __syncthreads();
  if (t == 0) {
    int old = atomicAdd((int*)(ws + OFF_CNT), 1);
    tailflag = (old == 7);
  }
  __syncthreads();
  if (!tailflag) return;
  __threadfence();
  for (int i = t; i < 8 * 128; i += 640)
    hp[i >> 7][i & 127] = aloadf(ws + OFF_H1PART + i);
  __syncthreads();
  for (int i = t; i < WAY * 128; i += 640) {
    int w = i >> 7, n = i & 127;
    float a = ws[OFF_H1P + w * 128 + n] + b1[n];
#pragma unroll
    for (int k = 0; k < 8; ++k) a += hp[k][n];
    h1all[w][n] = fmaxf(a, 0.f);
  }
  __syncthreads();
  for (int i = t; i < WAY * 64; i += 640) {
    int w = i >> 6, n = i & 63;
    float acc = b2[n];
#pragma unroll 8
    for (int k = 0; k < 128; ++k)
      acc = fmaf(h1all[w][k], W2[(size_t)k * 64 + n], acc);
    h2all[w][n] = fmaxf(acc, 0.f);
  }
  __syncthreads();
  if (t < WAY) {
    int w = t;
    float lg[5];
#pragma unroll
    for (int r = 0; r < 5; ++r) {
      float acc = b3[r];
      for (int k = 0; k < 64; ++k) acc = fmaf(h2all[w][k], W3[k * 5 + r], acc);
      lg[r] = acc;
    }
    double m = lg[0];
    for (int i = 1; i < 5; ++i) m = fmax(m, (double)lg[i]);
    double se = 0.0, cv = 0.0;
    for (int i = 0; i < 5; ++i) { double e = exp((double)lg[i] - m); se += e; cv += e * 0.2 * (double)(i + 1); }
    double c = cv / se;
    ws[OFF_C + w] = (float)c;
    double p2 = ((const double*)(ws + OFF_P2RAW))[w];
    double u2;
    double beta = expmap_scale(c, p2, &u2);
    ws[OFF_BETA + w] = (float)beta;
    ((double*)(ws + OFF_X2D))[w] = u2;
  }
}

#define GEMM_COMPUTE2(BUF)                                            \
  {                                                                   \
    const float* qr = &S[BUF][q][0];                                  \
    const float* x0r = &S[BUF][16 + w0][0];                           \
    const float* x1r = &S[BUF][16 + w1][0];                           \
    _Pragma("unroll")                                                 \
    for (int kk = 0; kk < 64; kk += 4) {                              \
      float4 qv = *(const float4*)(qr + kk);                          \
      float4 x0v = *(const float4*)(x0r + kk);                        \
      float4 x1v = *(const float4*)(x1r + kk);                       \
      c0x = fmaf(qv.x, x0v.x, c0x); c0y = fmaf(qv.y, x0v.y, c0y);     \
      c0z = fmaf(qv.z, x0v.z, c0z); c0w = fmaf(qv.w, x0v.w, c0w);     \
      c1x = fmaf(qv.x, x1v.x, c1x); c1y = fmaf(qv.y, x1v.y, c1y);     \
      c1z = fmaf(qv.z, x1v.z, c1z); c1w = fmaf(qv.w, x1v.w, c1w);     \
    }                                                                 \
  }

// grid 256 x 256: block = 16 q-rows x 32 ways; thread = (q, wpair); f32 dist epilogue.
// mode 0: -> DIS. mode 1: -> out (f32 fast path; reference is f32 anyway).
__global__ __launch_bounds__(256) void k_gemm(const float* __restrict__ X, const float* __restrict__ Qm,
                                              float* __restrict__ ws, int mode, float* __restrict__ out) {
  __shared__ float S[2][48][68];   // rows 0..15 = Q tile, rows 16..47 = X (32 ways)
  int t = threadIdx.x;
  int q0 = blockIdx.x * 16;
  int rr = t >> 4, qd = t & 15;
  const float* srcA = Qm + (size_t)(q0 + rr) * DIM + qd * 4;
  const float* srcB = X + (size_t)rr * DIM + qd * 4;
  const float* srcC = X + (size_t)(rr + 16) * DIM + qd * 4;
  float4 a0 = *(const float4*)srcA;
  float4 a1 = *(const float4*)srcB;
  float4 a2 = *(const float4*)srcC;
  *(float4*)&S[0][rr][qd * 4] = a0;
  *(float4*)&S[0][16 + rr][qd * 4] = a1;
  *(float4*)&S[0][32 + rr][qd * 4] = a2;
  __syncthreads();
  a0 = *(const float4*)(srcA + 64);
  a1 = *(const float4*)(srcB + 64);
  a2 = *(const float4*)(srcC + 64);
  float4 b0 = {0.f,0.f,0.f,0.f}, b1v = b0, b2v = b0;
  int q = t & 15, wp = t >> 4;
  int w0 = wp * 2, w1 = wp * 2 + 1;
  float c0x = 0.f, c0y = 0.f, c0z = 0.f, c0w = 0.f;
  float c1x = 0.f, c1y = 0.f, c1z = 0.f, c1w = 0.f;
#pragma unroll
  for (int c = 0; c < 10; c += 2) {
    GEMM_COMPUTE2(0)
    if (c + 2 < 10) {
      size_t kc = (size_t)(c + 2) * 64;
      b0 = *(const float4*)(srcA + kc);
      b1v = *(const float4*)(srcB + kc);
      b2v = *(const float4*)(srcC + kc);
    }
    if (c + 1 < 10) {
      *(float4*)&S[1][rr][qd * 4] = a0;
      *(float4*)&S[1][16 + rr][qd * 4] = a1;
      *(float4*)&S[1][32 + rr][qd * 4] = a2;
      __syncthreads();
      GEMM_COMPUTE2(1)
      if (c + 3 < 10) {
        size_t kc = (size_t)(c + 3) * 64;
        a0 = *(const float4*)(srcA + kc);
        a1 = *(const float4*)(srcB + kc);
        a2 = *(const float4*)(srcC + kc);
      }
      if (c + 2 < 10) {
        *(float4*)&S[0][rr][qd * 4] = b0;
        *(float4*)&S[0][16 + rr][qd * 4] = b1v;
        *(float4*)&S[0][32 + rr][qd * 4] = b2v;
        __syncthreads();
      }
    }
  }
  float acc0 = (c0x + c0y) + (c0z + c0w);
  float acc1 = (c1x + c1y) + (c1z + c1w);
  int qq = q0 + q;
  const double* q2d = (const double*)(ws + OFF_Q2D);
  float q2f = (float)q2d[qq];
  if (mode == 0) {
    const double* x2d = (const double*)(ws + OFF_X2D);
    float d0 = dist_f32(ws[OFF_C + w0], ws[OFF_BETA + w0] * acc0, (float)x2d[w0], q2f);
    float d1 = dist_f32(ws[OFF_C + w1], ws[OFF_BETA + w1] * acc1, (float)x2d[w1], q2f);
    ws[OFF_G + (size_t)w0 * NQ + qq] = d0;
    ws[OFF_G + (size_t)w1 * NQ + qq] = d1;
  } else {
    const double* u2arr = (const double*)(ws + OFF_X2D2);
    float d0 = dist_f32(ws[OFF_C + w0], acc0, (float)u2arr[w0], q2f);
    float d1 = dist_f32(ws[OFF_C + w1], acc1, (float)u2arr[w1], q2f);
    out[(size_t)qq * WAY + w0] = -d0 * (1.f / 16.f);
    out[(size_t)qq * WAY + w1] = -d1 * (1.f / 16.f);
  }
}

// grid 32 x 1024: per-way top-10 + S/U + stats from precomputed DIS
__global__ __launch_bounds__(1024) void k_topkA(float* __restrict__ ws) {
  __shared__ double sredS[16], sredU[16];
  __shared__ float cval[160];
  __shared__ int cidx[160];
  __shared__ float qvsh[RNEAR];
  __shared__ int qjsh[RNEAR];
  __shared__ float colsh[RNEAR][33];
  __shared__ float pcpart[RNEAR];
  int w = blockIdx.x, t = threadIdx.x;
  int lane = t & 63, wid = t >> 6;
  int* nidx = (int*)(ws + OFF_NIDX);
  const float* gb = ws + OFF_G + (size_t)w * NQ;
  float v0 = gb[t], v1 = gb[1024 + t], v2 = gb[2048 + t], v3 = gb[3072 + t];
  unsigned tk = 0;
  double s = (double)v0 + (double)v1 + (double)v2 + (double)v3;
  double u = (t < RNEAR) ? (double)v0 : 0.0;
  s = wave_sum_d(s);
  u = wave_sum_d(u);
  if (lane == 0) { sredS[wid] = s; sredU[wid] = u; }
  for (int r = 0; r < RNEAR; ++r) {
    float lv = INFINITY; int li = 0x7fffffff;
    if (!(tk & 1u) && (v0 < lv || (v0 == lv && t < li)))        { lv = v0; li = t; }
    if (!(tk & 2u) && (v1 < lv || (v1 == lv && 1024 + t < li))) { lv = v1; li = 1024 + t; }
    if (!(tk & 4u) && (v2 < lv || (v2 == lv && 2048 + t < li))) { lv = v2; li = 2048 + t; }
    if (!(tk & 8u) && (v3 < lv || (v3 == lv && 3072 + t < li))) { lv = v3; li = 3072 + t; }
#pragma unroll
    for (int o = 32; o > 0; o >>= 1) {
      float ov = __shfl_xor(lv, o, 64);
      int oi = __shfl_xor(li, o, 64);
      if (ov < lv || (ov == lv && oi < li)) { lv = ov; li = oi; }
    }
    if (lane == 0) { cval[wid * RNEAR + r] = lv; cidx[wid * RNEAR + r] = li; }
    if ((li & 1023) == t) tk |= 1u << (li >> 10);
  }
  __syncthreads();
  if (t == 0) {
    double S = 0.0, U = 0.0;
    for (int k = 0; k < 16; ++k) { S += sredS[k]; U += sredU[k]; }
    ws[OFF_S + w] = (float)S;
    ws[OFF_U + w] = (float)U;
  }
  if (t < 64) {
    float c0 = cval[t], c1 = cval[t + 64];
    int i0 = cidx[t], i1 = cidx[t + 64];
    float c2 = (t < 32) ? cval[t + 128] : INFINITY;
    int i2 = (t < 32) ? cidx[t + 128] : 0x7fffffff;
    unsigned m = 0;
    for (int r = 0; r < RNEAR; ++r) {
      float lv = INFINITY; int li = 0x7fffffff;
      if (!(m & 1u) && (c0 < lv || (c0 == lv && i0 < li))) { lv = c0; li = i0; }
      if (!(m & 2u) && (c1 < lv || (c1 == lv && i1 < li))) { lv = c1; li = i1; }
      if (!(m & 4u) && (c2 < lv || (c2 == lv && i2 < li))) { lv = c2; li = i2; }
#pragma unroll
      for (int o = 32; o > 0; o >>= 1) {
        float ov = __shfl_xor(lv, o, 64);
        int oi = __shfl_xor(li, o, 64);
        if (ov < lv || (ov == lv && oi < li)) { lv = ov; li = oi; }
      }
      if (lane == 0) { qvsh[r] = lv; qjsh[r] = li; }
      if (i0 == li) m |= 1u;
      if (i1 == li) m |= 2u;
      if (i2 == li) m |= 4u;
    }
  }
  __syncthreads();
  if (t < WAY * RNEAR) {
    int j = t >> 5, w2 = t & 31;
    colsh[j][w2] = ws[OFF_G + (size_t)w2 * NQ + qjsh[j]];
  }
  __syncthreads();
  if (t < RNEAR) {
    double cs = 0.0, pc = 0.0;
    for (int w2 = 0; w2 < WAY; ++w2) {
      float dv = colsh[t][w2];
      cs += dv;
      if (w2 < w) pc += dv;
    }
    ws[OFF_RR + w * 22 + t] = qvsh[t];
    ws[OFF_RR + w * 22 + RNEAR + t] = (float)((cs - qvsh[t]) / (double)(WAY - 1));
    ws[OFF_NID + w * RNEAR + t] = qvsh[t];
    nidx[w * RNEAR + t] = qjsh[t];
    pcpart[t] = (float)pc;
  }
  __syncthreads();
  if (t == 0) {
    double spc = 0.0, sn = 0.0;
    for (int j = 0; j < RNEAR; ++j) { spc += pcpart[j]; sn += qvsh[j]; }
    double S = (double)ws[OFF_S + w];
    ws[OFF_RR + w * 22 + 20] = (float)((S - sn) / (double)(NQ - RNEAR));
    ws[OFF_SPC + w] = (float)spc;
  }
}

// grid 32 x 640: per-way refine MLP + tmp/expmap -> TP
__global__ __launch_bounds__(640) void k_refB(const float* __restrict__ Qm,
                                              const float* __restrict__ Wr1, const float* __restrict__ br1,
                                              const float* __restrict__ Wr2, const float* __restrict__ br2,
                                              float* __restrict__ ws) {
  __shared__ float Ssh[WAY], Ush[WAY];
  __shared__ float rrl[22];
  __shared__ int qj[RNEAR];
  __shared__ float hr[RNEAR], orsh[11], iw[RNEAR];
  __shared__ float onw_sh;
  __shared__ double p2red[10];
  __shared__ double gshd;
  int w = blockIdx.x, t = threadIdx.x;
  int lane = t & 63, wid = t >> 6;  // 10 waves
  const int* nidx = (const int*)(ws + OFF_NIDX);
  if (t < WAY) { Ssh[t] = ws[OFF_S + t]; Ush[t] = ws[OFF_U + t]; }
  if (t >= 64 && t < 64 + 22) rrl[t - 64] = ws[OFF_RR + w * 22 + (t - 64)];
  if (t >= 96 && t < 96 + RNEAR) qj[t - 96] = nidx[w * RNEAR + (t - 96)];
  __syncthreads();
  if (t == 0) {
    double pref = 0.0, suf = 0.0;
    for (int j = 0; j < w; ++j) pref += (double)Ssh[j];
    for (int j = w + 1; j < WAY; ++j) suf += (double)Ssh[j] - (double)Ush[j];
    double spc = (double)ws[OFF_SPC + w];
    rrl[21] = (float)((pref - spc + suf) / ((double)(WAY - 1) * (double)(NQ - RNEAR)));
  }
  __syncthreads();
  if (t < RNEAR) {
    float a = br1[t];
    for (int k = 0; k < 22; ++k) a = fmaf(rrl[k], Wr1[k * RNEAR + t], a);
    hr[t] = fmaxf(a, 0.f);
  }
  __syncthreads();
  if (t < 11) {
    float a = br2[t];
    for (int k = 0; k < RNEAR; ++k) a = fmaf(hr[k], Wr2[k * 11 + t], a);
    orsh[t] = a;
  }
  __syncthreads();
  if (t == 0) {
    double m = orsh[0];
    for (int i = 1; i < RNEAR; ++i) m = fmax(m, (double)orsh[i]);
    double se = 0.0; double e[RNEAR];
    for (int i = 0; i < RNEAR; ++i) { e[i] = exp((double)orsh[i] - m); se += e[i]; }
    for (int i = 0; i < RNEAR; ++i) iw[i] = (float)(e[i] / se);
    onw_sh = (float)(1.0 / (1.0 + exp(-(double)orsh[10])));
  }
  __syncthreads();
  float onwv = onw_sh;
  float wd = 0.f;
#pragma unroll
  for (int j = 0; j < RNEAR; ++j)
    wd = fmaf(Qm[(size_t)qj[j] * DIM + t], iw[j], wd);
  float a0 = ws[OFF_PROTOS + w * DIM + t] * onwv + wd * (1.f - onwv);
  double ls = (double)a0 * a0;
  ls = wave_sum_d(ls);
  if (lane == 0) p2red[wid] = ls;
  __syncthreads();
  if (t == 0) {
    double p2 = 0.0;
#pragma unroll
    for (int k = 0; k < 10; ++k) p2 += p2red[k];
    double u22;
    gshd = expmap_scale((double)ws[OFF_C + w], p2, &u22);
    ((double*)(ws + OFF_X2D2))[w] = u22;
  }
  __syncthreads();
  ws[OFF_TP + w * DIM + t] = (float)gshd * a0;
}

extern "C" void kernel_launch(void* const* d_in, const int* in_sizes, int n_in,
                              void* d_out, int out_size, void* d_ws, size_t ws_size,
                              hipStream_t stream) {
  (void)in_sizes; (void)n_in; (void)out_size; (void)ws_size;
  const float* shot = (const float*)d_in[0];
  const float* qry  = (const float*)d_in[1];
  const float* W1   = (const float*)d_in[2];
  const float* b1   = (const float*)d_in[3];
  const float* W2   = (const float*)d_in[4];
  const float* b2   = (const float*)d_in[5];
  const float* W3   = (const float*)d_in[6];
  const float* b3   = (const float*)d_in[7];
  const float* Wr1  = (const float*)d_in[8];
  const float* br1  = (const float*)d_in[9];
  const float* Wr2  = (const float*)d_in[10];
  const float* br2  = (const float*)d_in[11];
  float* ws = (float*)d_ws;
  float* out = (float*)d_out;

  hipLaunchKernelGGL(k_fuse1, dim3(128), dim3(640), 0, stream, qry, shot, W1, ws);
  hipLaunchKernelGGL(k_amw1,  dim3(8), dim3(640), 0, stream, W1, b1, W2, b2, W3, b3, ws);
  hipLaunchKernelGGL(k_gemm,  dim3(256), dim3(256), 0, stream, ws + OFF_PROTOS, qry, ws, 0, out);
  hipLaunchKernelGGL(k_topkA, dim3(32), dim3(1024), 0, stream, ws);
  hipLaunchKernelGGL(k_refB,  dim3(32), dim3(640), 0, stream, qry, Wr1, br1, Wr2, br2, ws);
  hipLaunchKernelGGL(k_gemm,  dim3(256), dim3(256), 0, stream, ws + OFF_TP, qry, ws, 1, out);
}

// Round 23
// 77.895 us; speedup vs baseline: 1.1878x; 1.1878x over previous
//
#include <hip/hip_runtime.h>
#include <math.h>

#define NSHOT 5
#define WAY 32
#define DIM 640
#define NQ 4096
#define RNEAR 10

// ---- workspace layout (float offsets), ~1.08 MB ----
constexpr int OFF_PROTOS = 0;        // 32*640
constexpr int OFF_QPART  = 20480;    // 128*640 column partial sums (incl. shot fold)
constexpr int OFF_C      = 102400;   // 32
constexpr int OFF_BETA   = 102432;   // 32
constexpr int OFF_S      = 102464;   // 32
constexpr int OFF_U      = 102496;   // 32
constexpr int OFF_NID    = 102528;   // 32*10
constexpr int OFF_RR     = 102848;   // 32*22
constexpr int OFF_SPC    = 103552;   // 32
constexpr int OFF_H1P    = 103584;   // 32*128 (per-way pr·W1a)
constexpr int OFF_TP     = 107680;   // 32*640
constexpr int OFF_G      = 128160;   // 32*4096 f32 DISTANCES (written by gemm mode 0)
constexpr int OFF_NIDX   = 259232;   // 32*10 ints
constexpr int OFF_Q2D    = 259556;   // double[4096] (byte-offset %8 == 0)
constexpr int OFF_X2D    = 267748;   // double[32] (proto_p norm^2)
constexpr int OFF_X2D2   = 267812;   // double[32] (test_proto norm^2)
constexpr int OFF_P2RAW  = 267876;   // double[32] (raw proto norm^2)
constexpr int OFF_H1PART = 268000;   // 8*128 way-independent h1 partials

__device__ __forceinline__ double wave_sum_d(double v) {
#pragma unroll
  for (int o = 32; o > 0; o >>= 1) v += __shfl_down(v, o, 64);
  return v;
}

// f32 fast distance — selection AND output paths (reference computes dis_mat in f32;
// validated on HW in R22: absmax 0.0 with this epilogue)
__device__ __forceinline__ float dist_f32(float c, float xdotq, float u2, float q2) {
  const float EPSf = 1e-5f;
  float sc = sqrtf(c);
  float nq = sqrtf(q2);
  float nf = fmaxf(nq, EPSf);
  float th = tanhf(sc * nf);
  float al = th / (sc * nf);
  float ny = fmaxf(al * nq, EPSf);
  float mx = 0.999f / sc;
  if (ny > mx) al *= mx / ny;
  float y2 = al * al * q2;
  float uy = -al * xdotq;
  float A = 1.f + 2.f * c * uy + c * y2;
  float B = 1.f - c * u2;
  float den = fmaxf(1.f + 2.f * c * uy + c * c * u2 * y2, EPSf);
  float num2 = fmaxf(A * A * u2 + 2.f * A * B * uy + B * B * y2, 0.f);
  float n = sqrtf(num2) / den;
  float arg = sc * n;
  arg = fminf(fmaxf(arg, 0.f), 1.f - 1e-5f);
  return (1.f / sc) * logf((1.f + arg) / (1.f - arg));
}

__device__ __forceinline__ double expmap_scale(double c, double p2, double* u2out) {
  double sc = sqrt(c);
  double ntrue = sqrt(p2);
  double nf = fmax(ntrue, 1e-5);
  double th = tanh(sc * nf);
  double s0 = th / (sc * nf);
  double ny = fmax(s0 * ntrue, 1e-5);
  double mx = 0.999 / sc;
  if (ny > mx) s0 *= mx / ny;
  *u2out = s0 * s0 * p2;
  return s0;
}

// grid 128 x 640: protos + P2RAW + H1P (b<32), per-row q2, QPART (+shot fold)
__global__ __launch_bounds__(640) void k_fuse1(const float* __restrict__ Qm,
                                               const float* __restrict__ shot,
                                               const float* __restrict__ W1, float* ws) {
  __shared__ double q2w[32][10];
  __shared__ double psred[10];
  __shared__ float pr[DIM];
  __shared__ float h1pp[5][128];
  int b = blockIdx.x, t = threadIdx.x;
  int lane = t & 63, wid = t >> 6;  // 10 waves
  float protoval = 0.f;
  if (b < WAY) {
    float s = 0.f;
#pragma unroll
    for (int s5 = 0; s5 < NSHOT; ++s5) s += shot[(size_t)(s5 * WAY + b) * DIM + t];
    protoval = s * 0.2f;
    pr[t] = protoval;
    ws[OFF_PROTOS + b * DIM + t] = protoval;
    double pv2 = (double)protoval * protoval;
    pv2 = wave_sum_d(pv2);
    if (lane == 0) psred[wid] = pv2;
  }
  int r0 = b * 32;
  float colacc = 0.f;
  for (int r = 0; r < 32; ++r) {
    float v = Qm[(size_t)(r0 + r) * DIM + t];
    colacc += v;
    double sq = (double)v * v;
    sq = wave_sum_d(sq);
    if (lane == 0) q2w[r][wid] = sq;
  }
  ws[OFF_QPART + b * DIM + t] = colacc + 5.f * protoval;
  __syncthreads();
  if (t < 32) {
    double s = 0.0;
#pragma unroll
    for (int k = 0; k < 10; ++k) s += q2w[t][k];
    ((double*)(ws + OFF_Q2D))[r0 + t] = s;
  }
  if (b < WAY) {
    int n = t & 127, s = t >> 7;
    int k0 = s * 128;
    float acc = 0.f;
#pragma unroll 8
    for (int k = k0; k < k0 + 128; ++k) acc = fmaf(pr[k], W1[(size_t)k * 128 + n], acc);
    h1pp[s][n] = acc;
    __syncthreads();
    if (t < 128)
      ws[OFF_H1P + b * 128 + t] = h1pp[0][t] + h1pp[1][t] + h1pp[2][t] + h1pp[3][t] + h1pp[4][t];
    if (t == 0) {
      double p2 = 0.0;
#pragma unroll
      for (int k = 0; k < 10; ++k) p2 += psred[k];
      ((double*)(ws + OFF_P2RAW))[b] = p2;
    }
  }
}

// grid 8 x 320: way-independent ctrl work, done ONCE (R19-proven)
__global__ __launch_bounds__(320) void k_amw1(const float* __restrict__ W1, float* ws) {
  __shared__ float part_am[4][80];
  __shared__ float am_s[80];
  __shared__ float h1part[2][128];
  int j = blockIdx.x, t = threadIdx.x;
  {
    int c = t % 80, pg = t / 80;   // 4 p-groups x 32
    const float* base = ws + OFF_QPART + j * 80 + c;
    int p0 = pg * 32;
    float a0 = 0.f, a1 = 0.f, a2 = 0.f, a3 = 0.f;
#pragma unroll 8
    for (int p = 0; p < 32; p += 4) {
      a0 += base[(size_t)(p0 + p + 0) * DIM];
      a1 += base[(size_t)(p0 + p + 1) * DIM];
      a2 += base[(size_t)(p0 + p + 2) * DIM];
      a3 += base[(size_t)(p0 + p + 3) * DIM];
    }
    part_am[pg][c] = (a0 + a1) + (a2 + a3);
  }
  __syncthreads();
  if (t < 80)
    am_s[t] = (part_am[0][t] + part_am[1][t] + part_am[2][t] + part_am[3][t]) * (1.f / 4256.f);
  __syncthreads();
  if (t < 256) {
    int n = t & 127, kh = t >> 7;      // 2 k-halves x 40
    int kbase = j * 80 + kh * 40;
    float acc = 0.f;
#pragma unroll 8
    for (int k = 0; k < 40; ++k)
      acc = fmaf(am_s[kh * 40 + k], W1[(size_t)(DIM + kbase + k) * 128 + n], acc);
    h1part[kh][n] = acc;
  }
  __syncthreads();
  if (t < 128) ws[OFF_H1PART + j * 128 + t] = h1part[0][t] + h1part[1][t];
}

// grid 32 x 128: per-way MLP tail (R19-proven)
__global__ __launch_bounds__(128) void k_ctrl2(const float* __restrict__ b1,
                                               const float* __restrict__ W2, const float* __restrict__ b2,
                                               const float* __restrict__ W3, const float* __restrict__ b3,
                                               float* ws) {
  __shared__ float h1s[128];
  __shared__ float h2p[2][64];
  __shared__ float h2s[64], lg[5];
  int w = blockIdx.x, t = threadIdx.x;
  {
    float a = ws[OFF_H1P + w * 128 + t] + b1[t];
#pragma unroll
    for (int j = 0; j < 8; ++j) a += ws[OFF_H1PART + j * 128 + t];
    h1s[t] = fmaxf(a, 0.f);
  }
  __syncthreads();
  {
    int n = t & 63, kh = t >> 6;       // 2 k-halves x 64
    int k0 = kh * 64;
    float acc = 0.f;
#pragma unroll 8
    for (int k = 0; k < 64; ++k)
      acc = fmaf(h1s[k0 + k], W2[(size_t)(k0 + k) * 64 + n], acc);
    h2p[kh][n] = acc;
  }
  __syncthreads();
  if (t < 64) h2s[t] = fmaxf(h2p[0][t] + h2p[1][t] + b2[t], 0.f);
  __syncthreads();
  if (t < 5) {
    float acc = b3[t];
    for (int k = 0; k < 64; ++k) acc = fmaf(h2s[k], W3[k * 5 + t], acc);
    lg[t] = acc;
  }
  __syncthreads();
  if (t == 0) {
    double m = lg[0];
    for (int i = 1; i < 5; ++i) m = fmax(m, (double)lg[i]);
    double se = 0.0, cv = 0.0;
    for (int i = 0; i < 5; ++i) { double e = exp((double)lg[i] - m); se += e; cv += e * 0.2 * (double)(i + 1); }
    double c = cv / se;
    ws[OFF_C + w] = (float)c;
    double p2 = ((const double*)(ws + OFF_P2RAW))[w];
    double u2;
    double beta = expmap_scale(c, p2, &u2);
    ws[OFF_BETA + w] = (float)beta;
    ((double*)(ws + OFF_X2D))[w] = u2;
  }
}

#define GEMM_COMPUTE2(BUF)                                            \
  {                                                                   \
    const float* qr = &S[BUF][q][0];                                  \
    const float* x0r = &S[BUF][16 + w0][0];                           \
    const float* x1r = &S[BUF][16 + w1][0];                           \
    _Pragma("unroll")                                                 \
    for (int kk = 0; kk < 64; kk += 4) {                              \
      float4 qv = *(const float4*)(qr + kk);                          \
      float4 x0v = *(const float4*)(x0r + kk);                        \
      float4 x1v = *(const float4*)(x1r + kk);                       \
      c0x = fmaf(qv.x, x0v.x, c0x); c0y = fmaf(qv.y, x0v.y, c0y);     \
      c0z = fmaf(qv.z, x0v.z, c0z); c0w = fmaf(qv.w, x0v.w, c0w);     \
      c1x = fmaf(qv.x, x1v.x, c1x); c1y = fmaf(qv.y, x1v.y, c1y);     \
      c1z = fmaf(qv.z, x1v.z, c1z); c1w = fmaf(qv.w, x1v.w, c1w);     \
    }                                                                 \
  }

// grid 256 x 256: block = 16 q-rows x 32 ways; thread = (q, wpair). f32 dist
// epilogue on both modes (mode 0 -> DIS, mode 1 -> out).
__global__ __launch_bounds__(256) void k_gemm(const float* __restrict__ X, const float* __restrict__ Qm,
                                              float* __restrict__ ws, int mode, float* __restrict__ out) {
  __shared__ float S[2][48][68];   // rows 0..15 = Q tile, rows 16..47 = X (32 ways)
  int t = threadIdx.x;
  int q0 = blockIdx.x * 16;
  int rr = t >> 4, qd = t & 15;
  const float* srcA = Qm + (size_t)(q0 + rr) * DIM + qd * 4;
  const float* srcB = X + (size_t)rr * DIM + qd * 4;
  const float* srcC = X + (size_t)(rr + 16) * DIM + qd * 4;
  float4 a0 = *(const float4*)srcA;
  float4 a1 = *(const float4*)srcB;
  float4 a2 = *(const float4*)srcC;
  *(float4*)&S[0][rr][qd * 4] = a0;
  *(float4*)&S[0][16 + rr][qd * 4] = a1;
  *(float4*)&S[0][32 + rr][qd * 4] = a2;
  __syncthreads();
  a0 = *(const float4*)(srcA + 64);
  a1 = *(const float4*)(srcB + 64);
  a2 = *(const float4*)(srcC + 64);
  float4 b0 = {0.f,0.f,0.f,0.f}, b1v = b0, b2v = b0;
  int q = t & 15, wp = t >> 4;
  int w0 = wp * 2, w1 = wp * 2 + 1;
  float c0x = 0.f, c0y = 0.f, c0z = 0.f, c0w = 0.f;
  float c1x = 0.f, c1y = 0.f, c1z = 0.f, c1w = 0.f;
#pragma unroll
  for (int c = 0; c < 10; c += 2) {
    GEMM_COMPUTE2(0)
    if (c + 2 < 10) {
      size_t kc = (size_t)(c + 2) * 64;
      b0 = *(const float4*)(srcA + kc);
      b1v = *(const float4*)(srcB + kc);
      b2v = *(const float4*)(srcC + kc);
    }
    if (c + 1 < 10) {
      *(float4*)&S[1][rr][qd * 4] = a0;
      *(float4*)&S[1][16 + rr][qd * 4] = a1;
      *(float4*)&S[1][32 + rr][qd * 4] = a2;
      __syncthreads();
      GEMM_COMPUTE2(1)
      if (c + 3 < 10) {
        size_t kc = (size_t)(c + 3) * 64;
        a0 = *(const float4*)(srcA + kc);
        a1 = *(const float4*)(srcB + kc);
        a2 = *(const float4*)(srcC + kc);
      }
      if (c + 2 < 10) {
        *(float4*)&S[0][rr][qd * 4] = b0;
        *(float4*)&S[0][16 + rr][qd * 4] = b1v;
        *(float4*)&S[0][32 + rr][qd * 4] = b2v;
        __syncthreads();
      }
    }
  }
  float acc0 = (c0x + c0y) + (c0z + c0w);
  float acc1 = (c1x + c1y) + (c1z + c1w);
  int qq = q0 + q;
  const double* q2d = (const double*)(ws + OFF_Q2D);
  float q2f = (float)q2d[qq];
  if (mode == 0) {
    const double* x2d = (const double*)(ws + OFF_X2D);
    float d0 = dist_f32(ws[OFF_C + w0], ws[OFF_BETA + w0] * acc0, (float)x2d[w0], q2f);
    float d1 = dist_f32(ws[OFF_C + w1], ws[OFF_BETA + w1] * acc1, (float)x2d[w1], q2f);
    ws[OFF_G + (size_t)w0 * NQ + qq] = d0;
    ws[OFF_G + (size_t)w1 * NQ + qq] = d1;
  } else {
    const double* u2arr = (const double*)(ws + OFF_X2D2);
    float d0 = dist_f32(ws[OFF_C + w0], acc0, (float)u2arr[w0], q2f);
    float d1 = dist_f32(ws[OFF_C + w1], acc1, (float)u2arr[w1], q2f);
    out[(size_t)qq * WAY + w0] = -d0 * (1.f / 16.f);
    out[(size_t)qq * WAY + w1] = -d1 * (1.f / 16.f);
  }
}

// grid 32 x 1024: per-way top-10 + S/U + stats from precomputed DIS
__global__ __launch_bounds__(1024) void k_topkA(float* __restrict__ ws) {
  __shared__ double sredS[16], sredU[16];
  __shared__ float cval[160];
  __shared__ int cidx[160];
  __shared__ float qvsh[RNEAR];
  __shared__ int qjsh[RNEAR];
  __shared__ float colsh[RNEAR][33];
  __shared__ float pcpart[RNEAR];
  int w = blockIdx.x, t = threadIdx.x;
  int lane = t & 63, wid = t >> 6;
  int* nidx = (int*)(ws + OFF_NIDX);
  const float* gb = ws + OFF_G + (size_t)w * NQ;
  float v0 = gb[t], v1 = gb[1024 + t], v2 = gb[2048 + t], v3 = gb[3072 + t];
  unsigned tk = 0;
  double s = (double)v0 + (double)v1 + (double)v2 + (double)v3;
  double u = (t < RNEAR) ? (double)v0 : 0.0;
  s = wave_sum_d(s);
  u = wave_sum_d(u);
  if (lane == 0) { sredS[wid] = s; sredU[wid] = u; }
  for (int r = 0; r < RNEAR; ++r) {
    float lv = INFINITY; int li = 0x7fffffff;
    if (!(tk & 1u) && (v0 < lv || (v0 == lv && t < li)))        { lv = v0; li = t; }
    if (!(tk & 2u) && (v1 < lv || (v1 == lv && 1024 + t < li))) { lv = v1; li = 1024 + t; }
    if (!(tk & 4u) && (v2 < lv || (v2 == lv && 2048 + t < li))) { lv = v2; li = 2048 + t; }
    if (!(tk & 8u) && (v3 < lv || (v3 == lv && 3072 + t < li))) { lv = v3; li = 3072 + t; }
#pragma unroll
    for (int o = 32; o > 0; o >>= 1) {
      float ov = __shfl_xor(lv, o, 64);
      int oi = __shfl_xor(li, o, 64);
      if (ov < lv || (ov == lv && oi < li)) { lv = ov; li = oi; }
    }
    if (lane == 0) { cval[wid * RNEAR + r] = lv; cidx[wid * RNEAR + r] = li; }
    if ((li & 1023) == t) tk |= 1u << (li >> 10);
  }
  __syncthreads();
  if (t == 0) {
    double S = 0.0, U = 0.0;
    for (int k = 0; k < 16; ++k) { S += sredS[k]; U += sredU[k]; }
    ws[OFF_S + w] = (float)S;
    ws[OFF_U + w] = (float)U;
  }
  if (t < 64) {
    float c0 = cval[t], c1 = cval[t + 64];
    int i0 = cidx[t], i1 = cidx[t + 64];
    float c2 = (t < 32) ? cval[t + 128] : INFINITY;
    int i2 = (t < 32) ? cidx[t + 128] : 0x7fffffff;
    unsigned m = 0;
    for (int r = 0; r < RNEAR; ++r) {
      float lv = INFINITY; int li = 0x7fffffff;
      if (!(m & 1u) && (c0 < lv || (c0 == lv && i0 < li))) { lv = c0; li = i0; }
      if (!(m & 2u) && (c1 < lv || (c1 == lv && i1 < li))) { lv = c1; li = i1; }
      if (!(m & 4u) && (c2 < lv || (c2 == lv && i2 < li))) { lv = c2; li = i2; }
#pragma unroll
      for (int o = 32; o > 0; o >>= 1) {
        float ov = __shfl_xor(lv, o, 64);
        int oi = __shfl_xor(li, o, 64);
        if (ov < lv || (ov == lv && oi < li)) { lv = ov; li = oi; }
      }
      if (lane == 0) { qvsh[r] = lv; qjsh[r] = li; }
      if (i0 == li) m |= 1u;
      if (i1 == li) m |= 2u;
      if (i2 == li) m |= 4u;
    }
  }
  __syncthreads();
  if (t < WAY * RNEAR) {
    int j = t >> 5, w2 = t & 31;
    colsh[j][w2] = ws[OFF_G + (size_t)w2 * NQ + qjsh[j]];
  }
  __syncthreads();
  if (t < RNEAR) {
    double cs = 0.0, pc = 0.0;
    for (int w2 = 0; w2 < WAY; ++w2) {
      float dv = colsh[t][w2];
      cs += dv;
      if (w2 < w) pc += dv;
    }
    ws[OFF_RR + w * 22 + t] = qvsh[t];
    ws[OFF_RR + w * 22 + RNEAR + t] = (float)((cs - qvsh[t]) / (double)(WAY - 1));
    ws[OFF_NID + w * RNEAR + t] = qvsh[t];
    nidx[w * RNEAR + t] = qjsh[t];
    pcpart[t] = (float)pc;
  }
  __syncthreads();
  if (t == 0) {
    double spc = 0.0, sn = 0.0;
    for (int j = 0; j < RNEAR; ++j) { spc += pcpart[j]; sn += qvsh[j]; }
    double S = (double)ws[OFF_S + w];
    ws[OFF_RR + w * 22 + 20] = (float)((S - sn) / (double)(NQ - RNEAR));
    ws[OFF_SPC + w] = (float)spc;
  }
}

// grid 32 x 640: per-way refine MLP + tmp/expmap -> TP
__global__ __launch_bounds__(640) void k_refB(const float* __restrict__ Qm,
                                              const float* __restrict__ Wr1, const float* __restrict__ br1,
                                              const float* __restrict__ Wr2, const float* __restrict__ br2,
                                              float* __restrict__ ws) {
  __shared__ float Ssh[WAY], Ush[WAY];
  __shared__ float rrl[22];
  __shared__ int qj[RNEAR];
  __shared__ float hr[RNEAR], orsh[11], iw[RNEAR];
  __shared__ float onw_sh;
  __shared__ double p2red[10];
  __shared__ double gshd;
  int w = blockIdx.x, t = threadIdx.x;
  int lane = t & 63, wid = t >> 6;  // 10 waves
  const int* nidx = (const int*)(ws + OFF_NIDX);
  if (t < WAY) { Ssh[t] = ws[OFF_S + t]; Ush[t] = ws[OFF_U + t]; }
  if (t >= 64 && t < 64 + 22) rrl[t - 64] = ws[OFF_RR + w * 22 + (t - 64)];
  if (t >= 96 && t < 96 + RNEAR) qj[t - 96] = nidx[w * RNEAR + (t - 96)];
  __syncthreads();
  if (t == 0) {
    double pref = 0.0, suf = 0.0;
    for (int j = 0; j < w; ++j) pref += (double)Ssh[j];
    for (int j = w + 1; j < WAY; ++j) suf += (double)Ssh[j] - (double)Ush[j];
    double spc = (double)ws[OFF_SPC + w];
    rrl[21] = (float)((pref - spc + suf) / ((double)(WAY - 1) * (double)(NQ - RNEAR)));
  }
  __syncthreads();
  if (t < RNEAR) {
    float a = br1[t];
    for (int k = 0; k < 22; ++k) a = fmaf(rrl[k], Wr1[k * RNEAR + t], a);
    hr[t] = fmaxf(a, 0.f);
  }
  __syncthreads();
  if (t < 11) {
    float a = br2[t];
    for (int k = 0; k < RNEAR; ++k) a = fmaf(hr[k], Wr2[k * 11 + t], a);
    orsh[t] = a;
  }
  __syncthreads();
  if (t == 0) {
    double m = orsh[0];
    for (int i = 1; i < RNEAR; ++i) m = fmax(m, (double)orsh[i]);
    double se = 0.0; double e[RNEAR];
    for (int i = 0; i < RNEAR; ++i) { e[i] = exp((double)orsh[i] - m); se += e[i]; }
    for (int i = 0; i < RNEAR; ++i) iw[i] = (float)(e[i] / se);
    onw_sh = (float)(1.0 / (1.0 + exp(-(double)orsh[10])));
  }
  __syncthreads();
  float onwv = onw_sh;
  float wd = 0.f;
#pragma unroll
  for (int j = 0; j < RNEAR; ++j)
    wd = fmaf(Qm[(size_t)qj[j] * DIM + t], iw[j], wd);
  float a0 = ws[OFF_PROTOS + w * DIM + t] * onwv + wd * (1.f - onwv);
  double ls = (double)a0 * a0;
  ls = wave_sum_d(ls);
  if (lane == 0) p2red[wid] = ls;
  __syncthreads();
  if (t == 0) {
    double p2 = 0.0;
#pragma unroll
    for (int k = 0; k < 10; ++k) p2 += p2red[k];
    double u22;
    gshd = expmap_scale((double)ws[OFF_C + w], p2, &u22);
    ((double*)(ws + OFF_X2D2))[w] = u22;
  }
  __syncthreads();
  ws[OFF_TP + w * DIM + t] = (float)gshd * a0;
}

extern "C" void kernel_launch(void* const* d_in, const int* in_sizes, int n_in,
                              void* d_out, int out_size, void* d_ws, size_t ws_size,
                              hipStream_t stream) {
  (void)in_sizes; (void)n_in; (void)out_size; (void)ws_size;
  const float* shot = (const float*)d_in[0];
  const float* qry  = (const float*)d_in[1];
  const float* W1   = (const float*)d_in[2];
  const float* b1   = (const float*)d_in[3];
  const float* W2   = (const float*)d_in[4];
  const float* b2   = (const float*)d_in[5];
  const float* W3   = (const float*)d_in[6];
  const float* b3   = (const float*)d_in[7];
  const float* Wr1  = (const float*)d_in[8];
  const float* br1  = (const float*)d_in[9];
  const float* Wr2  = (const float*)d_in[10];
  const float* br2  = (const float*)d_in[11];
  float* ws = (float*)d_ws;
  float* out = (float*)d_out;

  hipLaunchKernelGGL(k_fuse1, dim3(128), dim3(640), 0, stream, qry, shot, W1, ws);
  hipLaunchKernelGGL(k_amw1,  dim3(8), dim3(320), 0, stream, W1, ws);
  hipLaunchKernelGGL(k_ctrl2, dim3(32), dim3(128), 0, stream, b1, W2, b2, W3, b3, ws);
  hipLaunchKernelGGL(k_gemm,  dim3(256), dim3(256), 0, stream, ws + OFF_PROTOS, qry, ws, 0, out);
  hipLaunchKernelGGL(k_topkA, dim3(32), dim3(1024), 0, stream, ws);
  hipLaunchKernelGGL(k_refB,  dim3(32), dim3(640), 0, stream, qry, Wr1, br1, Wr2, br2, ws);
  hipLaunchKernelGGL(k_gemm,  dim3(256), dim3(256), 0, stream, ws + OFF_TP, qry, ws, 1, out);
}